// Round 1
// baseline (316.725 us; speedup 1.0000x reference)
//
#include <hip/hip_runtime.h>
#include <math.h>

#define N    8192
#define INF_ 512
#define ZD   128
#define CC   64
#define HD   50
#define EPSF 1e-8f

__device__ __forceinline__ float softplus_f(float t) {
    // numerically stable: max(t,0) + log1p(exp(-|t|))
    return fmaxf(t, 0.f) + log1pf(expf(-fabsf(t)));
}

// ---- grouping kernels ----
__global__ void k_count(const int* __restrict__ c, int* __restrict__ counts) {
    int i = blockIdx.x * 256 + threadIdx.x;
    if (i < N) atomicAdd(&counts[c[i]], 1);
}

__global__ void k_scan(const int* __restrict__ counts, int* __restrict__ offsets) {
    int t = threadIdx.x;   // 64 threads, one per category
    int s = 0;
    for (int q = 0; q < t; ++q) s += counts[q];
    offsets[t] = s;
}

__global__ void k_scatter(const int* __restrict__ c, const int* __restrict__ offsets,
                          int* __restrict__ cursors, int* __restrict__ grouped) {
    int i = blockIdx.x * 256 + threadIdx.x;
    if (i < N) {
        int cat = c[i];
        int pos = atomicAdd(&cursors[cat], 1);
        grouped[offsets[cat] + pos] = i;
    }
}

// ---- h = relu(x @ W1 + b1), padded to 64 cols ----
// one wave per row; lane = output index k (50 active)
__global__ __launch_bounds__(256) void k_h(const float* __restrict__ x,
                                           const float* __restrict__ W1,
                                           const float* __restrict__ b1,
                                           float* __restrict__ h) {
    int lane = threadIdx.x & 63;
    int n    = blockIdx.x * 4 + (threadIdx.x >> 6);
    int k    = (lane < HD) ? lane : 0;     // clamp to stay in-bounds
    const float* xr = x + (size_t)n * INF_;
    float acc = b1[k];
    #pragma unroll 4
    for (int d = 0; d < INF_; ++d)
        acc = fmaf(xr[d], W1[d * HD + k], acc);
    h[n * 64 + lane] = (lane < HD) ? fmaxf(acc, 0.f) : 0.f;
}

// ---- per-row: fx, fz, u, logT.  128 threads/block, rows in grouped order ----
__global__ __launch_bounds__(128) void k_row(const float* __restrict__ z,
                                             const int*   __restrict__ c,
                                             const float* __restrict__ W2,
                                             const float* __restrict__ b2,
                                             const float* __restrict__ Wz,
                                             const float* __restrict__ bz,
                                             const float* __restrict__ Ws,
                                             const float* __restrict__ h,
                                             const int*   __restrict__ grouped,
                                             float* __restrict__ fz_g,
                                             float* __restrict__ u_g,
                                             float* __restrict__ logT) {
    __shared__ float sh[HD];
    __shared__ float sz[ZD];
    __shared__ float sfx[ZD];
    __shared__ float red[ZD];
    int e = threadIdx.x;
    int n = grouped[blockIdx.x];           // grouped order -> Ws[cat] L2 locality
    if (e < HD) sh[e] = h[n * 64 + e];
    sz[e] = z[(size_t)n * ZD + e];
    __syncthreads();

    // fx = h @ W2 + b2
    float fxv = b2[e];
    #pragma unroll 5
    for (int k = 0; k < HD; ++k)
        fxv = fmaf(sh[k], W2[k * ZD + e], fxv);
    sfx[e] = fxv;

    // fz = z @ Wz + bz
    float fzv = bz[e];
    #pragma unroll 8
    for (int d = 0; d < ZD; ++d)
        fzv = fmaf(sz[d], Wz[d * ZD + e], fzv);
    fz_g[(size_t)n * ZD + e] = fzv;
    __syncthreads();

    // u = fx @ Ws[cat]
    int cat = c[n];
    const float* Wc = Ws + (size_t)cat * ZD * ZD;
    float uv = 0.f;
    #pragma unroll 8
    for (int d = 0; d < ZD; ++d)
        uv = fmaf(sfx[d], Wc[d * ZD + e], uv);
    u_g[(size_t)n * ZD + e] = uv;

    // T = softplus(dot(u, fz))
    red[e] = uv * fzv;
    __syncthreads();
    for (int s = 64; s >= 1; s >>= 1) {
        if (e < s) red[e] += red[e + s];
        __syncthreads();
    }
    if (e == 0) logT[n] = logf(softplus_f(red[0]) + EPSF);
}

// ---- neg_T + final output.  128 threads/block, one block per sample i ----
__global__ __launch_bounds__(128) void k_neg(const int*   __restrict__ c,
                                             const int*   __restrict__ offsets,
                                             const int*   __restrict__ counts,
                                             const int*   __restrict__ grouped,
                                             const float* __restrict__ fz_g,
                                             const float* __restrict__ u_g,
                                             const float* __restrict__ logT,
                                             float* __restrict__ out) {
    __shared__ __align__(16) float su[ZD];
    __shared__ float red[128];
    int t = threadIdx.x;
    int i = grouped[blockIdx.x];           // grouped order -> fz group L2 locality
    int cat = c[i];
    int off = offsets[cat];
    int cnt = counts[cat];
    su[t] = u_g[(size_t)i * ZD + t];
    __syncthreads();

    const float4* su4 = (const float4*)su;
    float local = 0.f;
    for (int jj = t; jj < cnt; jj += 128) {
        int j = grouped[off + jj];
        const float4* f4 = (const float4*)(fz_g + (size_t)j * ZD);
        float dot = 0.f;
        #pragma unroll
        for (int q = 0; q < ZD / 4; ++q) {
            float4 a = su4[q];
            float4 b = f4[q];
            dot = fmaf(a.x, b.x, fmaf(a.y, b.y, fmaf(a.z, b.z, fmaf(a.w, b.w, dot))));
        }
        local += softplus_f(dot);
    }
    red[t] = local;
    __syncthreads();
    for (int s = 64; s >= 1; s >>= 1) {
        if (t < s) red[t] += red[t + s];
        __syncthreads();
    }
    if (t == 0) out[i] = logT[i] - logf(red[0] / (float)cnt + EPSF);
}

extern "C" void kernel_launch(void* const* d_in, const int* in_sizes, int n_in,
                              void* d_out, int out_size, void* d_ws, size_t ws_size,
                              hipStream_t stream) {
    const float* x  = (const float*)d_in[0];
    const int*   c  = (const int*)  d_in[1];
    const float* z  = (const float*)d_in[2];
    const float* W1 = (const float*)d_in[3];
    const float* b1 = (const float*)d_in[4];
    const float* W2 = (const float*)d_in[5];
    const float* b2 = (const float*)d_in[6];
    const float* Wz = (const float*)d_in[7];
    const float* bz = (const float*)d_in[8];
    const float* Ws = (const float*)d_in[9];
    float* out = (float*)d_out;

    // workspace layout
    float* ws      = (float*)d_ws;
    float* h       = ws;                       // N*64
    float* fz_g    = h + (size_t)N * 64;       // N*128
    float* u_g     = fz_g + (size_t)N * ZD;    // N*128
    float* logT    = u_g + (size_t)N * ZD;     // N
    int*   counts  = (int*)(logT + N);         // 64
    int*   offsets = counts + CC;              // 64
    int*   cursors = offsets + CC;             // 64
    int*   grouped = cursors + CC;             // N

    // zero counts + offsets + cursors (ws is poisoned 0xAA each call)
    hipMemsetAsync(counts, 0, 3 * CC * sizeof(int), stream);

    k_count  <<<N / 256, 256, 0, stream>>>(c, counts);
    k_scan   <<<1, CC, 0, stream>>>(counts, offsets);
    k_scatter<<<N / 256, 256, 0, stream>>>(c, offsets, cursors, grouped);
    k_h      <<<N / 4, 256, 0, stream>>>(x, W1, b1, h);
    k_row    <<<N, 128, 0, stream>>>(z, c, W2, b2, Wz, bz, Ws, h, grouped,
                                     fz_g, u_g, logT);
    k_neg    <<<N, 128, 0, stream>>>(c, offsets, counts, grouped, fz_g, u_g,
                                     logT, out);
}

// Round 2
// 226.502 us; speedup vs baseline: 1.3983x; 1.3983x over previous
//
#include <hip/hip_runtime.h>
#include <math.h>

#define N_   8192
#define IN_  512
#define ZD   128
#define CC   64
#define HD   50
#define EPSF 1e-8f

__device__ __forceinline__ float softplus_f(float t) {
    // numerically stable: max(t,0) + log1p(exp(-|t|))
    return fmaxf(t, 0.f) + log1pf(expf(-fabsf(t)));
}

// ---- grouping: histogram + exclusive scan + cursor init, single block ----
__global__ __launch_bounds__(256) void k_group(const int* __restrict__ c,
                                               int* __restrict__ counts,
                                               int* __restrict__ offsets,
                                               int* __restrict__ cursors) {
    __shared__ int hist[CC];
    int t = threadIdx.x;
    if (t < CC) hist[t] = 0;
    __syncthreads();
    for (int i = t; i < N_; i += 256) atomicAdd(&hist[c[i]], 1);
    __syncthreads();
    if (t < CC) {
        int s = 0;
        for (int q = 0; q < t; ++q) s += hist[q];
        counts[t]  = hist[t];
        offsets[t] = s;
        cursors[t] = 0;
    }
}

__global__ __launch_bounds__(256) void k_scatter(const int* __restrict__ c,
                                                 const int* __restrict__ offsets,
                                                 int* __restrict__ cursors,
                                                 int* __restrict__ grouped) {
    int i = blockIdx.x * 256 + threadIdx.x;
    if (i < N_) {
        int cat = c[i];
        int pos = atomicAdd(&cursors[cat], 1);
        grouped[offsets[cat] + pos] = i;
    }
}

// ---- W1 transpose: W1t[k][d] = W1[d][k], k padded to 64 (zeros) ----
__global__ __launch_bounds__(256) void k_w1t(const float* __restrict__ W1,
                                             float* __restrict__ W1t) {
    int idx = blockIdx.x * 256 + threadIdx.x;   // 64*512 = 32768
    int k = idx >> 9, d = idx & 511;
    W1t[idx] = (k < HD) ? W1[d * HD + k] : 0.f;
}

// ---- h = relu(x @ W1 + b1), tiled GEMM. 16 rows/block, 256 threads ----
__global__ __launch_bounds__(256) void k_h(const float* __restrict__ x,
                                           const float* __restrict__ W1t,
                                           const float* __restrict__ b1,
                                           float* __restrict__ h) {
    __shared__ float sx[16 * IN_];              // 32 KB
    int tid  = threadIdx.x;
    int row0 = blockIdx.x * 16;
    const float4* x4  = (const float4*)(x + (size_t)row0 * IN_);
    float4*       sx4 = (float4*)sx;
    #pragma unroll
    for (int f = 0; f < 8; ++f) sx4[tid + f * 256] = x4[tid + f * 256];
    __syncthreads();

    int k = tid & 63, rg = tid >> 6;            // 4 row-groups of 4 rows
    const float4* w4 = (const float4*)(W1t + (size_t)k * IN_);
    float acc[4] = {0.f, 0.f, 0.f, 0.f};
    for (int d4 = 0; d4 < IN_ / 4; ++d4) {
        float4 w = w4[d4];
        #pragma unroll
        for (int r = 0; r < 4; ++r) {
            float4 a = sx4[(rg * 4 + r) * (IN_ / 4) + d4];
            acc[r] = fmaf(w.x, a.x, fmaf(w.y, a.y, fmaf(w.z, a.z, fmaf(w.w, a.w, acc[r]))));
        }
    }
    float bb = (k < HD) ? b1[k] : 0.f;
    #pragma unroll
    for (int r = 0; r < 4; ++r) {
        int n = row0 + rg * 4 + r;
        h[n * 64 + k] = (k < HD) ? fmaxf(acc[r] + bb, 0.f) : 0.f;
    }
}

// ---- fx = h @ W2 + b2.  32 rows/block, 16 accs/thread ----
__global__ __launch_bounds__(256) void k_fx(const float* __restrict__ h,
                                            const float* __restrict__ W2,
                                            const float* __restrict__ b2,
                                            float* __restrict__ fx) {
    __shared__ float sh[32 * 64];               // 8 KB
    int tid  = threadIdx.x;
    int row0 = blockIdx.x * 32;
    const float4* h4 = (const float4*)(h + (size_t)row0 * 64);
    float4*       s4 = (float4*)sh;
    #pragma unroll
    for (int f = 0; f < 2; ++f) s4[tid + f * 256] = h4[tid + f * 256];
    __syncthreads();

    int e = tid & 127, rg = tid >> 7;
    float bb = b2[e];
    float acc[16];
    #pragma unroll
    for (int r = 0; r < 16; ++r) acc[r] = bb;
    for (int d = 0; d < HD; ++d) {
        float wv = W2[d * ZD + e];
        #pragma unroll
        for (int r = 0; r < 16; ++r)
            acc[r] = fmaf(sh[(rg * 16 + r) * 64 + d], wv, acc[r]);
    }
    #pragma unroll
    for (int r = 0; r < 16; ++r)
        fx[(size_t)(row0 + rg * 16 + r) * ZD + e] = acc[r];
}

// ---- fz = z @ Wz + bz.  32 rows/block, 16 accs/thread ----
__global__ __launch_bounds__(256) void k_fz(const float* __restrict__ z,
                                            const float* __restrict__ Wz,
                                            const float* __restrict__ bz,
                                            float* __restrict__ fz) {
    __shared__ float sz[32 * ZD];               // 16 KB
    int tid  = threadIdx.x;
    int row0 = blockIdx.x * 32;
    const float4* z4 = (const float4*)(z + (size_t)row0 * ZD);
    float4*       s4 = (float4*)sz;
    #pragma unroll
    for (int f = 0; f < 4; ++f) s4[tid + f * 256] = z4[tid + f * 256];
    __syncthreads();

    int e = tid & 127, rg = tid >> 7;
    float bb = bz[e];
    float acc[16];
    #pragma unroll
    for (int r = 0; r < 16; ++r) acc[r] = bb;
    for (int d = 0; d < ZD; ++d) {
        float wv = Wz[d * ZD + e];
        #pragma unroll
        for (int r = 0; r < 16; ++r)
            acc[r] = fmaf(sz[(rg * 16 + r) * ZD + d], wv, acc[r]);
    }
    #pragma unroll
    for (int r = 0; r < 16; ++r)
        fz[(size_t)(row0 + rg * 16 + r) * ZD + e] = acc[r];
}

// ---- u = fx @ Ws[cat], batched per category. 32 grouped rows/block ----
#define MAXT_U 16
__global__ __launch_bounds__(256) void k_u(const float* __restrict__ fx,
                                           const float* __restrict__ Ws,
                                           const int* __restrict__ grouped,
                                           const int* __restrict__ offsets,
                                           const int* __restrict__ counts,
                                           float* __restrict__ u) {
    __shared__ float sfx[32 * ZD];              // 16 KB
    __shared__ int   srow[32];
    int tid = threadIdx.x;
    int cat = blockIdx.x >> 4, t = blockIdx.x & (MAXT_U - 1);
    int off = offsets[cat], cnt = counts[cat];
    int r0 = t * 32;
    if (r0 >= cnt) return;
    int m = min(32, cnt - r0);
    if (tid < 32) srow[tid] = (tid < m) ? grouped[off + r0 + tid] : -1;
    __syncthreads();

    float4* s4 = (float4*)sfx;
    #pragma unroll
    for (int f = 0; f < 4; ++f) {
        int idx = tid + f * 256;                // 0..1023
        int row = idx >> 5, q = idx & 31;
        int n = srow[row];
        s4[idx] = (n >= 0) ? ((const float4*)(fx + (size_t)n * ZD))[q]
                           : make_float4(0.f, 0.f, 0.f, 0.f);
    }
    __syncthreads();

    int e = tid & 127, rg = tid >> 7;
    const float* Wc = Ws + (size_t)cat * ZD * ZD;
    float acc[16];
    #pragma unroll
    for (int r = 0; r < 16; ++r) acc[r] = 0.f;
    for (int d = 0; d < ZD; ++d) {
        float wv = Wc[d * ZD + e];
        #pragma unroll
        for (int r = 0; r < 16; ++r)
            acc[r] = fmaf(sfx[(rg * 16 + r) * ZD + d], wv, acc[r]);
    }
    #pragma unroll
    for (int r = 0; r < 16; ++r) {
        int n = srow[rg * 16 + r];
        if (n >= 0) u[(size_t)n * ZD + e] = acc[r];
    }
}

// ---- logT[n] = log(softplus(dot(u[n], fz[n])) + eps).  1 wave/row ----
__global__ __launch_bounds__(256) void k_T(const float* __restrict__ u,
                                           const float* __restrict__ fz,
                                           float* __restrict__ logT) {
    int lane = threadIdx.x & 63;
    int n = blockIdx.x * 4 + (threadIdx.x >> 6);
    const float2* u2 = (const float2*)(u  + (size_t)n * ZD);
    const float2* f2 = (const float2*)(fz + (size_t)n * ZD);
    float2 a = u2[lane], b = f2[lane];
    float p = a.x * b.x + a.y * b.y;
    #pragma unroll
    for (int s = 32; s >= 1; s >>= 1) p += __shfl_down(p, s, 64);
    if (lane == 0) logT[n] = logf(softplus_f(p) + EPSF);
}

// ---- neg_T + output: 8 i-rows per block, stream group's fz rows ----
#define MAXT_N 64
__global__ __launch_bounds__(256) void k_neg(const int* __restrict__ grouped,
                                             const int* __restrict__ offsets,
                                             const int* __restrict__ counts,
                                             const float* __restrict__ u,
                                             const float* __restrict__ fz,
                                             const float* __restrict__ logT,
                                             float* __restrict__ out) {
    __shared__ float su[8 * ZD];                // 4 KB
    __shared__ int   srow[8];
    __shared__ float sred[4][8];
    int tid = threadIdx.x;
    int cat = blockIdx.x >> 6, t = blockIdx.x & (MAXT_N - 1);
    int off = offsets[cat], cnt = counts[cat];
    int r0 = t * 8;
    if (r0 >= cnt) return;
    int mI = min(8, cnt - r0);
    if (tid < 8) srow[tid] = (tid < mI) ? grouped[off + r0 + tid] : -1;
    __syncthreads();
    {
        int row = tid >> 5, q = tid & 31;       // 8 rows x 32 float4
        int n = srow[row];
        ((float4*)su)[tid] = (n >= 0) ? ((const float4*)(u + (size_t)n * ZD))[q]
                                      : make_float4(0.f, 0.f, 0.f, 0.f);
    }
    __syncthreads();

    const float4* su4 = (const float4*)su;
    float acc[8];
    #pragma unroll
    for (int r = 0; r < 8; ++r) acc[r] = 0.f;
    for (int jj = tid; jj < cnt; jj += 256) {
        int j = grouped[off + jj];
        const float4* f4 = (const float4*)(fz + (size_t)j * ZD);
        float dot[8];
        #pragma unroll
        for (int r = 0; r < 8; ++r) dot[r] = 0.f;
        #pragma unroll 4
        for (int q = 0; q < 32; ++q) {
            float4 b = f4[q];
            #pragma unroll
            for (int r = 0; r < 8; ++r) {
                float4 a = su4[r * 32 + q];
                dot[r] = fmaf(a.x, b.x, fmaf(a.y, b.y, fmaf(a.z, b.z, fmaf(a.w, b.w, dot[r]))));
            }
        }
        #pragma unroll
        for (int r = 0; r < 8; ++r) acc[r] += softplus_f(dot[r]);
    }
    // wave reduce each acc, then combine the 4 waves via LDS
    #pragma unroll
    for (int r = 0; r < 8; ++r) {
        float v = acc[r];
        #pragma unroll
        for (int s = 32; s >= 1; s >>= 1) v += __shfl_down(v, s, 64);
        acc[r] = v;
    }
    int lane = tid & 63, w = tid >> 6;
    if (lane == 0) {
        #pragma unroll
        for (int r = 0; r < 8; ++r) sred[w][r] = acc[r];
    }
    __syncthreads();
    if (tid < 8) {
        int n = srow[tid];
        if (n >= 0) {
            float s = sred[0][tid] + sred[1][tid] + sred[2][tid] + sred[3][tid];
            out[n] = logT[n] - logf(s / (float)cnt + EPSF);
        }
    }
}

extern "C" void kernel_launch(void* const* d_in, const int* in_sizes, int n_in,
                              void* d_out, int out_size, void* d_ws, size_t ws_size,
                              hipStream_t stream) {
    const float* x  = (const float*)d_in[0];
    const int*   c  = (const int*)  d_in[1];
    const float* z  = (const float*)d_in[2];
    const float* W1 = (const float*)d_in[3];
    const float* b1 = (const float*)d_in[4];
    const float* W2 = (const float*)d_in[5];
    const float* b2 = (const float*)d_in[6];
    const float* Wz = (const float*)d_in[7];
    const float* bz = (const float*)d_in[8];
    const float* Ws = (const float*)d_in[9];
    float* out = (float*)d_out;

    // workspace layout (floats)
    float* ws   = (float*)d_ws;
    float* W1t  = ws;                            // 64*512
    float* h    = W1t + 64 * IN_;                // N*64
    float* fx   = h   + (size_t)N_ * 64;         // N*128
    float* fz   = fx  + (size_t)N_ * ZD;         // N*128
    float* u    = fz  + (size_t)N_ * ZD;         // N*128
    float* logT = u   + (size_t)N_ * ZD;         // N
    int* counts  = (int*)(logT + N_);            // 64
    int* offsets = counts + CC;                  // 64
    int* cursors = offsets + CC;                 // 64
    int* grouped = cursors + CC;                 // N

    k_group  <<<1, 256, 0, stream>>>(c, counts, offsets, cursors);
    k_scatter<<<N_ / 256, 256, 0, stream>>>(c, offsets, cursors, grouped);
    k_w1t    <<<(64 * IN_) / 256, 256, 0, stream>>>(W1, W1t);
    k_h      <<<N_ / 16, 256, 0, stream>>>(x, W1t, b1, h);
    k_fx     <<<N_ / 32, 256, 0, stream>>>(h, W2, b2, fx);
    k_fz     <<<N_ / 32, 256, 0, stream>>>(z, Wz, bz, fz);
    k_u      <<<CC * MAXT_U, 256, 0, stream>>>(fx, Ws, grouped, offsets, counts, u);
    k_T      <<<N_ / 4, 256, 0, stream>>>(u, fz, logT);
    k_neg    <<<CC * MAXT_N, 256, 0, stream>>>(grouped, offsets, counts, u, fz, logT, out);
}